// Round 5
// baseline (86.322 us; speedup 1.0000x reference)
//
#include <hip/hip_runtime.h>

// VectorQuantiser on MI355X — fused single-pass design.
// Inputs:  d_in[0] = z_e fp32 (16*2048*256), d_in[1] = codebook fp32 (1024*256)
// Outputs (flat fp32): z_q [8388608] | similarity [33554432] | ids [32768] | loss [1]
//
//   A prep_cb:  codebook -> bf16 (ws) + nse + rsqe.
//   B fused:    one block = 64 rows x all 1024 codes.
//               Phase 1: reg-stage z_e fp32 -> bf16 swizzled LDS + row norms.
//               Phase 2: 8 col-iters x 4 K-steps of 16x16x32 bf16 MFMA;
//                        per col-iter epilogue writes sim and top-2-per-64-strip
//                        candidate encodings to LDS.  (acc reset AFTER the
//                        epilogue loops — round-4 bug was resetting inside the
//                        j-loop, zeroing 3/4 of the fragment before it was read.)
//               Phase 3: per-row argmin from LDS cand; fp32-exact rescore of
//                        near-ties; z_q gather, ids, per-block loss partial.
//   C finalize: deterministic tree-sum of 512 partials; loss = 1.25 * mean.

#define M_ROWS 32768
#define KCODES 1024
#define DDIM   256
#define ENC_BIG 33554432.0f

typedef __bf16 bf16_t;
typedef __attribute__((ext_vector_type(8))) bf16_t bf16x8;
typedef __attribute__((ext_vector_type(4))) float f32x4;

__device__ __forceinline__ unsigned short f2bf(float f) {
  unsigned u = __float_as_uint(f);
  u += 0x7FFFu + ((u >> 16) & 1u);   // round-to-nearest-even
  return (unsigned short)(u >> 16);
}

__device__ __forceinline__ float wave_sum(float p) {
#pragma unroll
  for (int o = 1; o < 64; o <<= 1) p += __shfl_xor(p, o);
  return p;
}
__device__ __forceinline__ float wave_min(float p) {
#pragma unroll
  for (int o = 1; o < 64; o <<= 1) p = fminf(p, __shfl_xor(p, o));
  return p;
}

// ---------------- Kernel A: codebook convert + norms ----------------
__global__ __launch_bounds__(256) void prep_cb_kernel(
    const float* __restrict__ cb, unsigned short* __restrict__ cbb,
    float* __restrict__ nse, float* __restrict__ rsqe)
{
  const int t = threadIdx.x;
  const int lane = t & 63;
  const int r = blockIdx.x * 4 + (t >> 6);           // wave per codebook row, 1024 rows
  const float4 e = ((const float4*)cb)[(size_t)r * 64 + lane];
  ushort4 u;
  u.x = f2bf(e.x); u.y = f2bf(e.y); u.z = f2bf(e.z); u.w = f2bf(e.w);
  ((ushort4*)cbb)[(size_t)r * 64 + lane] = u;
  float p = wave_sum(e.x*e.x + e.y*e.y + e.z*e.z + e.w*e.w);
  if (lane == 0) { nse[r] = p; rsqe[r] = 1.0f / sqrtf(p); }
}

// ---------------- Kernel B: fused GEMM + sim + argmin + z_q + loss ----------------
__global__ __launch_bounds__(256, 2) void fused_kernel(
    const float* __restrict__ ze, const float* __restrict__ cb,
    const unsigned short* __restrict__ cbb,
    const float* __restrict__ nse_g, const float* __restrict__ rsqe_g,
    float* __restrict__ sim, float* __restrict__ zq, float* __restrict__ ids,
    float* __restrict__ partials)
{
  __shared__ __attribute__((aligned(128))) unsigned short A[64 * 256];   // 32 KB, swizzled
  __shared__ __attribute__((aligned(128))) unsigned short Bt[128 * 64];  // 16 KB, swizzled
  __shared__ float s_nse[KCODES];     // 4 KB
  __shared__ float s_rsqe[KCODES];    // 4 KB
  __shared__ float s_rsqz[64];
  __shared__ float cand_lds[64 * 32]; // 8 KB: [row][strip*2 + {0,1}]
  __shared__ float s_part[4];

  const int t = threadIdx.x;
  const int wv = t >> 6, lane = t & 63;
  const int r16 = lane & 15, g = lane >> 4;
  const int wm = wv >> 1, wn = wv & 1;
  const long row0 = (long)blockIdx.x * 64;

  // preload codebook norm tables
  ((float4*)s_nse)[t]  = ((const float4*)nse_g)[t];
  ((float4*)s_rsqe)[t] = ((const float4*)rsqe_g)[t];

  // ---- Phase 1: stage A = z_e fp32 -> bf16, swizzled; row norms ----
#pragma unroll
  for (int k = 0; k < 16; ++k) {
    const int row = wv + 4 * k;
    const float4 z = ((const float4*)ze)[(row0 + row) * 64 + lane];
    const float p = wave_sum(z.x*z.x + z.y*z.y + z.z*z.z + z.w*z.w);
    if (lane == 0) s_rsqz[row] = 1.0f / sqrtf(p);
    ushort4 u;
    u.x = f2bf(z.x); u.y = f2bf(z.y); u.z = f2bf(z.z); u.w = f2bf(z.w);
    const int q  = lane >> 1;                              // logical 16B quad 0..31
    const int ph = (q & 24) | ((q ^ (row & 7)) & 7);       // XOR low-3 bits
    *(ushort4*)((char*)A + row * 512 + ph * 16 + (lane & 1) * 8) = u;
  }
  __syncthreads();

  // ---- Phase 2: col-loop GEMM ----
  f32x4 acc[2][4] = {};
  const int rr = lane >> 3, qq = lane & 7;
  const int sq = ((qq ^ rr) << 3);                         // pre-swizzled B source quad

  for (int kt = 0; kt < 32; ++kt) {                        // c = kt>>2, kk = kt&3
    const int c = kt >> 2, kk = kt & 3;
    const int col0 = c * 128, k0 = kk * 64;
    // stage B tile (128 codes x 64 K) via global_load_lds, pre-swizzled source
#pragma unroll
    for (int i = 0; i < 4; ++i) {
      const int rbase = wv * 32 + i * 8;
      const unsigned short* src = cbb + ((size_t)(col0 + rbase + rr)) * DDIM + k0 + sq;
      __builtin_amdgcn_global_load_lds((const __attribute__((address_space(1))) void*)src,
                                       (__attribute__((address_space(3))) void*)&Bt[rbase * 64],
                                       16, 0, 0);
    }
    __syncthreads();                                       // B ready (compiler drains vmcnt)
#pragma unroll
    for (int ks = 0; ks < 2; ++ks) {
      bf16x8 af[2], bf[4];
#pragma unroll
      for (int mi = 0; mi < 2; ++mi) {
        const int r = wm * 32 + mi * 16 + r16;
        const int ql = kk * 8 + ks * 4 + g;
        const int ph = (ql & 24) | ((ql ^ (r & 7)) & 7);
        af[mi] = *(const bf16x8*)((const char*)A + r * 512 + ph * 16);
      }
#pragma unroll
      for (int ni = 0; ni < 4; ++ni) {
        const int r = wn * 64 + ni * 16 + r16;
        const int ph = (ks * 4 + g) ^ (r & 7);
        bf[ni] = *(const bf16x8*)((const char*)Bt + r * 128 + ph * 16);
      }
#pragma unroll
      for (int mi = 0; mi < 2; ++mi)
#pragma unroll
        for (int ni = 0; ni < 4; ++ni)
          acc[mi][ni] = __builtin_amdgcn_mfma_f32_16x16x32_bf16(af[mi], bf[ni], acc[mi][ni], 0, 0, 0);
    }
    __syncthreads();                                       // protect Bt overwrite

    if (kk == 3) {
      // ---- per-col-iter epilogue: sim write + top-2 strip reduce ----
      const int strip = c * 2 + wn;                        // 0..15
#pragma unroll
      for (int mi = 0; mi < 2; ++mi) {
#pragma unroll
        for (int j = 0; j < 4; ++j) {
          const int rloc = wm * 32 + mi * 16 + g * 4 + j;
          const long row = row0 + rloc;
          const float rz = s_rsqz[rloc];
          float* so = sim + (size_t)row * KCODES + col0 + wn * 64 + r16;
          float e1 = ENC_BIG, e2 = ENC_BIG;
#pragma unroll
          for (int ni = 0; ni < 4; ++ni) {
            const int colk = col0 + wn * 64 + ni * 16 + r16;
            const float d = acc[mi][ni][j];
            so[ni * 16] = d * rz * s_rsqe[colk];
            const float v = s_nse[colk] - 2.0f * d;
            const float enc = floorf((v + 1024.0f) * 8.0f) * 1024.0f + (float)colk;
            if (enc < e1) { e2 = e1; e1 = enc; } else e2 = fminf(e2, enc);
          }
#pragma unroll
          for (int m = 1; m < 16; m <<= 1) {               // reduce within 16-lane group
            const float p1 = __shfl_xor(e1, m);
            const float p2 = __shfl_xor(e2, m);
            const float n1 = fminf(e1, p1);
            const float n2 = fminf(fmaxf(e1, p1), fminf(e2, p2));
            e1 = n1; e2 = n2;
          }
          if (r16 == 0) {
            cand_lds[rloc * 32 + strip * 2]     = e1;
            cand_lds[rloc * 32 + strip * 2 + 1] = e2;
          }
        }
      }
      // reset accumulators for the next col-iter (AFTER all j-components read)
#pragma unroll
      for (int mi = 0; mi < 2; ++mi)
#pragma unroll
        for (int ni = 0; ni < 4; ++ni)
          acc[mi][ni] = (f32x4)(0.0f);
    }
  }
  __syncthreads();

  // ---- Phase 3: per-row argmin + exact rescore + z_q + loss ----
  float loss_local = 0.0f;
  float4 zr = ((const float4*)ze)[(row0 + wv * 16) * 64 + lane];  // prefetch row 0
  for (int i = 0; i < 16; ++i) {
    const int rloc = wv * 16 + i;
    const long row = row0 + rloc;
    const float4 zc = zr;
    if (i < 15) zr = ((const float4*)ze)[(row + 1) * 64 + lane];

    const float e = (lane < 32) ? cand_lds[rloc * 32 + lane] : ENC_BIG;
    const float m_enc = wave_min(e);
    const float qmin  = floorf(m_enc * 0.0009765625f);
    const float ql    = floorf(e * 0.0009765625f);
    unsigned long long msk = __ballot(ql <= qmin + 16.0f); // margin ~2.0 dist units
    int kbest;
    if (__popcll(msk) == 1) {
      kbest = ((int)m_enc) & 1023;
    } else {
      float tbest = INFINITY; kbest = KCODES;
      while (msk) {                                        // wave-uniform
        const int lb = __ffsll(msk) - 1;
        msk &= msk - 1;
        const int kc = ((int)__shfl(e, lb)) & 1023;
        const float4 er = ((const float4*)cb)[(size_t)kc * 64 + lane];
        const float p = wave_sum(zc.x*er.x + zc.y*er.y + zc.z*er.z + zc.w*er.w);
        const float tv = s_nse[kc] - 2.0f * p;             // exact fp32 dist - nsz
        if (tv < tbest || (tv == tbest && kc < kbest)) { tbest = tv; kbest = kc; }
      }
    }

    const float4 er = ((const float4*)cb)[(size_t)kbest * 64 + lane];
    ((float4*)zq)[(size_t)row * 64 + lane] = er;
    const float dx = zc.x - er.x, dy = zc.y - er.y, dz = zc.z - er.z, dw = zc.w - er.w;
    const float ss = wave_sum(dx*dx + dy*dy + dz*dz + dw*dw);
    if (lane == 0) {
      ids[row] = (float)kbest;
      loss_local += sqrtf(ss);
    }
  }
  if (lane == 0) s_part[wv] = loss_local;
  __syncthreads();
  if (t == 0)
    partials[blockIdx.x] = (s_part[0] + s_part[1]) + (s_part[2] + s_part[3]);
}

// ---------------- Kernel C: finalize loss (deterministic tree sum) ----------------
__global__ __launch_bounds__(256) void finalize_kernel(
    const float* __restrict__ partials, float* __restrict__ out_loss)
{
  __shared__ float s[4];
  const int t = threadIdx.x;
  float p = partials[t] + partials[t + 256];               // 512 partials
  p = wave_sum(p);
  if ((t & 63) == 0) s[t >> 6] = p;
  __syncthreads();
  if (t == 0) out_loss[0] = 1.25f * ((s[0] + s[1]) + (s[2] + s[3])) / 32768.0f;
}

extern "C" void kernel_launch(void* const* d_in, const int* in_sizes, int n_in,
                              void* d_out, int out_size, void* d_ws, size_t ws_size,
                              hipStream_t stream) {
  const float* ze = (const float*)d_in[0];
  const float* cb = (const float*)d_in[1];

  float* out  = (float*)d_out;
  float* zq   = out;                    // 8388608
  float* sim  = out + 8388608;          // 33554432
  float* ids  = out + 41943040;         // 32768
  float* lout = out + 41975808;         // 1

  // ws layout (~530 KB, well under the confirmed >=800 KB floor)
  char* w = (char*)d_ws;
  unsigned short* cbb = (unsigned short*)w;      // 512 KB
  float* nse      = (float*)(w + 524288);        // 4 KB
  float* rsqe     = (float*)(w + 528384);        // 4 KB
  float* partials = (float*)(w + 532480);        // 2 KB (512 f32)

  prep_cb_kernel<<<256, 256, 0, stream>>>(cb, cbb, nse, rsqe);
  fused_kernel<<<512, 256, 0, stream>>>(ze, cb, cbb, nse, rsqe, sim, zq, ids, partials);
  finalize_kernel<<<1, 256, 0, stream>>>(partials, lout);
}